// Round 13
// baseline (122.728 us; speedup 1.0000x reference)
//
#include <hip/hip_runtime.h>
#include <hip/hip_bf16.h>

typedef unsigned short u16;
typedef unsigned int u32;
typedef __bf16 bf16x8 __attribute__((ext_vector_type(8)));
typedef u16 u16x8 __attribute__((ext_vector_type(8)));
typedef float floatx4 __attribute__((ext_vector_type(4)));

#define T_SEQ 2048
#define HDIM 64
#define NBH 32   // B*H

static __device__ __forceinline__ u16 f2b_rne(float x) {
    union { float f; u32 u; } c; c.f = x;
    u32 u = c.u;
    return (u16)((u + 0x7fffu + ((u >> 16) & 1u)) >> 16);
}
// packed f32x2 -> bf16x2 (RNE), single VALU op (no builtin on gfx950)
static __device__ __forceinline__ u32 cvtpk_bf16(float lo, float hi) {
    u32 r;
    asm("v_cvt_pk_bf16_f32 %0, %1, %2" : "=v"(r) : "v"(lo), "v"(hi));
    return r;
}

// async 16B/lane global->LDS; LDS dest = wave-uniform base + lane*16
#define GLOAD_LDS16(gp, lp)                                                      \
    __builtin_amdgcn_global_load_lds(                                            \
        (const __attribute__((address_space(1))) u32*)(gp),                      \
        (__attribute__((address_space(3))) u32*)(lp), 16, 0, 0)

// counted vmem waits (wait until <= N vmem ops outstanding)
#define WAIT_VM(N) asm volatile("s_waitcnt vmcnt(" #N ")" ::: "memory")

// ---- prepass, V-ONLY (K conversion moved into fattn's staging -- prep's
// serial traffic halves: 32MB read + 8MB write, ~7us floor).
// V fp32 [key][d] -> bf16 V^T [BH,D,T] with 32-chunk-preserving column
// permutation pos32(r) = ((r>>2)&3)*8 + ((r>>4)&1)*4 + (r&3) so the 16x16x32
// PV B-frag (lane quad, elems e) is one contiguous 16B region of V^T.
// Same permutation as r12 (refcheck'd). 2048 blocks x 256 thr, 32-key slabs.
__global__ __launch_bounds__(256) void prep(const float* __restrict__ v,
                                            u16* __restrict__ vt) {
    __shared__ __align__(16) u16 t2[32][72];       // [pos32][d], pad->72
    const int bh = blockIdx.y, t0 = blockIdx.x * 32;
    const int tid = threadIdx.x;

    const float* vsrc = v + ((size_t)bh * T_SEQ + t0) * HDIM;
#pragma unroll
    for (int p = 0; p < 2; p++) {
        int idx = p * 256 + tid;
        float4 f = ((const float4*)vsrc)[idx];
        int r = idx >> 4, c4 = (idx & 15) * 4;
        int pos = ((r >> 2) & 3) * 8 + ((r >> 4) & 1) * 4 + (r & 3);
        union { u32 w[2]; ushort4 s; } o;
        o.w[0] = cvtpk_bf16(f.x, f.y);
        o.w[1] = cvtpk_bf16(f.z, f.w);
        *(ushort4*)&t2[pos][c4] = o.s;
    }
    __syncthreads();

    // V^T store: 64 d x 32 pos, one 16B store per thread
    u16* dst = vt + (size_t)bh * HDIM * T_SEQ + t0;
    int d = tid >> 2, pb = tid & 3;
    union { u16x8 v8; u16 h[8]; } w;
#pragma unroll
    for (int i = 0; i < 8; i++) w.h[i] = t2[pb * 8 + i][d];
    *(u16x8*)(dst + (size_t)d * T_SEQ + pb * 8) = w.v8;
}

// ---- main kernel: r9 structure (best measured; 512 blocks x 512 thr /
// 8 waves, q-tile pair per block, wave=(tile,qhalf,khalf) 32qx32k quadrant,
// ring-4 LDS, pair loop, xcd-local bh, cvt_pk P-pack) with K STAGED DIRECTLY
// FROM THE FP32 INPUT (no kb workspace, no K prep):
//   per wave per tile: 2 coalesced float4 loads (rows wave*8+(lane>>3),
//   halves L*32 + (lane&7)*4) -> 4 cvt_pk -> 2 ds_write_b64 into the SAME
//   XOR-swizzled Kl layout (slot b at row r holds block b^(r&7)) -- reg-
//   staging lets us swizzle on the write side.
// Pair schedule: __syncthreads (full drain, wanted anyway) -> issue V-gloads
// + K-f32 loads for pair+2 -> compute(j) -> vmcnt(0) (loads had ~800cyc to
// cover ~200cyc L2 latency) -> cvt+ds_write K -> compute(j+1).
// Ring-4 disjointness: writes (j+2)&3,(j+3)&3 vs reads j&3,(j+1)&3.
// VGPR: r9's 64 + 16 kr = ~80 < 128 (16 waves/CU kept, no spill).
__global__ __launch_bounds__(512, 4) void fattn(const float* __restrict__ q,
                                                const float* __restrict__ k,
                                                const u16* __restrict__ vtb,
                                                float* __restrict__ out) {
    __shared__ __align__(16) u16 Kl[4][64 * 64];   // [key][d], XOR slot swizzle
    __shared__ __align__(16) u16 Vl[4][64 * 64];   // [d][perm-key], +d slot swizzle

    const int id = blockIdx.x;
    const int xcd = id & 7;
    const int u = id >> 3;                         // 0..63
    const int bh = xcd * 4 + (u & 3);              // 4 bh per XCD
    const int s = u >> 2;                          // 0..15
    const int pr = (s & 8) ? (s ^ 7) : s;          // cousin map: CU pairs (s,15-s)
    const int qtHi = 31 - pr, qtLo = pr;

    const int tid = threadIdx.x;
    const int wave = tid >> 6, lane = tid & 63;
    const int l15 = lane & 15, quad = lane >> 4;
    const int tile_sel = wave >> 2;                // 0: hi tile, 1: lo tile
    const int qhalf = (wave >> 1) & 1;             // which 32 q-rows
    const int khalf = wave & 1;                    // which 32 keys
    const int qt = tile_sel ? qtLo : qtHi;
    const int qrow_base = qt * 64 + qhalf * 32;

    const float* qp = q + (size_t)bh * T_SEQ * HDIM;
    const float* kp32 = k + (size_t)bh * T_SEQ * HDIM;
    const u16* vp = vtb + (size_t)bh * HDIM * T_SEQ;

    // staging geometry: row sr = wave*8 + (lane>>3), group g = lane&7.
    // V: one 16B GLOAD/wave/tile into Vl (linear dest, pre-swizzled source:
    //    LDS slot b at row r holds V perm-slot (b-r)&7).
    // K: 2 float4 loads (halves L*32 + g*4 of row sr) -> swizzled ds_write.
    const int sr = wave * 8 + (lane >> 3);
    const int g = lane & 7;
    const u16* vg0 = vp + (size_t)sr * T_SEQ + ((g - sr) & 7) * 8;
    const float* kgf = kp32 + (size_t)sr * HDIM + g * 4;

    auto stageV = [&](int j, int buf) {
        GLOAD_LDS16(vg0 + j * 64, &Vl[buf][wave * 512]);
    };
    auto loadK = [&](int j, float4 (&kr)[2]) {
        const float* p = kgf + (size_t)j * 64 * HDIM;
        kr[0] = *(const float4*)(p);
        kr[1] = *(const float4*)(p + 32);
    };
    auto writeK = [&](int buf, const float4 (&kr)[2]) {
        u16* base = &Kl[buf][sr * 64];
#pragma unroll
        for (int L = 0; L < 2; L++) {
            int b = L * 4 + (g >> 1);
            union { u32 w[2]; uint2 d2; } o;
            o.w[0] = cvtpk_bf16(kr[L].x, kr[L].y);
            o.w[1] = cvtpk_bf16(kr[L].z, kr[L].w);
            *(uint2*)(base + ((b ^ (sr & 7)) * 8 + (g & 1) * 4)) = o.d2;
        }
    };

    // Q fragments: qf[qb][kc], lane l15 holds Q[row][kc*32+quad*8..+7],
    // pre-scaled by scale*log2(e). Loaded before the pipeline prologue.
    const float SL2E = 0.125f * 1.44269504088896f;
    bf16x8 qf[2][2];
#pragma unroll
    for (int qb = 0; qb < 2; qb++) {
        const float* qrow = qp + (size_t)(qrow_base + qb * 16 + l15) * HDIM;
#pragma unroll
        for (int kc = 0; kc < 2; kc++) {
            const float4* p4 = (const float4*)(qrow + kc * 32 + quad * 8);
            float4 fa = p4[0], fb = p4[1];
            union { bf16x8 v; u16 s[8]; } cv;
            cv.s[0] = f2b_rne(fa.x * SL2E); cv.s[1] = f2b_rne(fa.y * SL2E);
            cv.s[2] = f2b_rne(fa.z * SL2E); cv.s[3] = f2b_rne(fa.w * SL2E);
            cv.s[4] = f2b_rne(fb.x * SL2E); cv.s[5] = f2b_rne(fb.y * SL2E);
            cv.s[6] = f2b_rne(fb.z * SL2E); cv.s[7] = f2b_rne(fb.w * SL2E);
            qf[qb][kc] = cv.v;
        }
    }

    // all-ones bf16 B-frag for MFMA row-sums
    union { u16 h[8]; bf16x8 v; } onesu;
#pragma unroll
    for (int i = 0; i < 8; i++) onesu.h[i] = 0x3F80;
    const bf16x8 ones = onesu.v;

    // prologue: pair {0,1} -- V async, K via regs, land in LDS
    {
        float4 krA[2], krB[2];
        stageV(0, 0);
        stageV(1, 1);
        loadK(0, krA);
        loadK(1, krB);
        WAIT_VM(0);
        writeK(0, krA);
        writeK(1, krB);
    }

    floatx4 o_acc[2][4];                           // [qb][dt], partial (khalf)
    floatx4 lsacc[2];                              // [qb] partial row-sums
#pragma unroll
    for (int qb = 0; qb < 2; qb++) {
        lsacc[qb] = (floatx4){0.f, 0.f, 0.f, 0.f};
#pragma unroll
        for (int dt = 0; dt < 4; dt++) o_acc[qb][dt] = (floatx4){0.f, 0.f, 0.f, 0.f};
    }

    // one tile's compute, register-minimal phase order (exact r9)
    auto compute = [&](int j) {
        const int cur = j & 3;
        const u16* Kc = Kl[cur];
        bf16x8 kf[2][2];                           // [kc][kb2]
#pragma unroll
        for (int kc = 0; kc < 2; kc++)
#pragma unroll
            for (int kb2 = 0; kb2 < 2; kb2++) {
                int rk = khalf * 32 + kb2 * 16 + l15;
                kf[kc][kb2] = *(const bf16x8*)(Kc + rk * 64 + ((kc * 4 + quad) ^ (rk & 7)) * 8);
            }
        floatx4 sacc[2][2];                        // [kb2][qb]
#pragma unroll
        for (int kb2 = 0; kb2 < 2; kb2++)
#pragma unroll
            for (int qb = 0; qb < 2; qb++) sacc[kb2][qb] = (floatx4){0.f, 0.f, 0.f, 0.f};
        __builtin_amdgcn_s_setprio(1);
#pragma unroll
        for (int kc = 0; kc < 2; kc++)
#pragma unroll
            for (int kb2 = 0; kb2 < 2; kb2++)
#pragma unroll
                for (int qb = 0; qb < 2; qb++)
                    sacc[kb2][qb] = __builtin_amdgcn_mfma_f32_16x16x32_bf16(
                        kf[kc][kb2], qf[qb][kc], sacc[kb2][qb], 0, 0, 0);
        __builtin_amdgcn_s_setprio(0);

        // P^T = exp2(S^T); causal mask on diagonal tile; pack via cvt_pk into
        // PV A-frags: elem e = kb2*4+rg <-> key khalf*32 + kb2*16 + quad*4 + rg
        union { bf16x8 v; u32 w[4]; } pk[2];
        if (j == qt) {
            const int key0 = khalf * 32 + quad * 4;
#pragma unroll
            for (int qb = 0; qb < 2; qb++) {
                const int gq = qhalf * 32 + qb * 16 + l15;
#pragma unroll
                for (int kb2 = 0; kb2 < 2; kb2++) {
                    float e0 = __builtin_amdgcn_exp2f(sacc[kb2][qb][0]);
                    float e1 = __builtin_amdgcn_exp2f(sacc[kb2][qb][1]);
                    float e2 = __builtin_amdgcn_exp2f(sacc[kb2][qb][2]);
                    float e3 = __builtin_amdgcn_exp2f(sacc[kb2][qb][3]);
                    int kbase = key0 + kb2 * 16;
                    if (kbase + 0 > gq) e0 = 0.f;
                    if (kbase + 1 > gq) e1 = 0.f;
                    if (kbase + 2 > gq) e2 = 0.f;
                    if (kbase + 3 > gq) e3 = 0.f;
                    pk[qb].w[kb2 * 2 + 0] = cvtpk_bf16(e0, e1);
                    pk[qb].w[kb2 * 2 + 1] = cvtpk_bf16(e2, e3);
                }
            }
        } else {
#pragma unroll
            for (int qb = 0; qb < 2; qb++)
#pragma unroll
                for (int kb2 = 0; kb2 < 2; kb2++) {
                    float e0 = __builtin_amdgcn_exp2f(sacc[kb2][qb][0]);
                    float e1 = __builtin_amdgcn_exp2f(sacc[kb2][qb][1]);
                    float e2 = __builtin_amdgcn_exp2f(sacc[kb2][qb][2]);
                    float e3 = __builtin_amdgcn_exp2f(sacc[kb2][qb][3]);
                    pk[qb].w[kb2 * 2 + 0] = cvtpk_bf16(e0, e1);
                    pk[qb].w[kb2 * 2 + 1] = cvtpk_bf16(e2, e3);
                }
        }

        // V fragments (read after sacc dies -- keeps the register peak low)
        const u16* Vc = Vl[cur];
        bf16x8 vf[4];
#pragma unroll
        for (int dt = 0; dt < 4; dt++) {
            int d = dt * 16 + l15;
            vf[dt] = *(const bf16x8*)(Vc + d * 64 + ((khalf * 4 + quad + d) & 7) * 8);
        }

        // O_partial += P . V (8 MFMA) ; row-sums += P . ones (2 MFMA)
        __builtin_amdgcn_s_setprio(1);
#pragma unroll
        for (int dt = 0; dt < 4; dt++)
#pragma unroll
            for (int qb = 0; qb < 2; qb++)
                o_acc[qb][dt] = __builtin_amdgcn_mfma_f32_16x16x32_bf16(
                    pk[qb].v, vf[dt], o_acc[qb][dt], 0, 0, 0);
        lsacc[0] = __builtin_amdgcn_mfma_f32_16x16x32_bf16(pk[0].v, ones, lsacc[0], 0, 0, 0);
        lsacc[1] = __builtin_amdgcn_mfma_f32_16x16x32_bf16(pk[1].v, ones, lsacc[1], 0, 0, 0);
        __builtin_amdgcn_s_setprio(0);
    };

    // pair loop: one full-drain barrier per 2 tiles; K lands mid-pair
    for (int j = 0; j <= qtHi; j += 2) {
        __syncthreads();                           // vm+lgkm drain + barrier:
                                                   // pair {j,j+1} fully in LDS
        const bool s2 = (j + 2 <= qtHi), s3 = (j + 3 <= qtHi);
        float4 krA[2], krB[2];
        if (s2) { stageV(j + 2, (j + 2) & 3); loadK(j + 2, krA); }
        if (s3) { stageV(j + 3, (j + 3) & 3); loadK(j + 3, krB); }

        if (j <= qt) compute(j);                   // wave-uniform guards

        if (s2 || s3) WAIT_VM(0);                  // loads covered by compute(j)
        if (s2) writeK((j + 2) & 3, krA);
        if (s3) writeK((j + 3) & 3, krB);

        if (j + 1 <= qtHi && j + 1 <= qt) compute(j + 1);
    }

    // ---- epilogue: khalf pair-reduce via LDS, normalize, store ----
    // lsacc[qb][rg] = partial row-sum for q = qrow_base + qb*16 + quad*4 + rg
    // (identical across l15) -- exactly o_acc's row indexing.
    __syncthreads();                               // main-loop LDS use complete
    const int r = wave >> 1;                       // pair region 0..3
    float* xch = ((r & 2) ? (float*)&Vl[0][0] : (float*)&Kl[0][0]) + (r & 1) * 2560;
    floatx4* xv = (floatx4*)xch;                   // [plane 0..9][lane] 16B, conflict-free
    if (khalf == 0) {
#pragma unroll
        for (int qb = 0; qb < 2; qb++) {
#pragma unroll
            for (int dt = 0; dt < 4; dt++) xv[(qb * 4 + dt) * 64 + lane] = o_acc[qb][dt];
            xv[(8 + qb) * 64 + lane] = lsacc[qb];
        }
    }
    __syncthreads();
    if (khalf == 1) {
        float* op = out + (size_t)bh * T_SEQ * HDIM;
#pragma unroll
        for (int qb = 0; qb < 2; qb++) {
#pragma unroll
            for (int dt = 0; dt < 4; dt++) o_acc[qb][dt] += xv[(qb * 4 + dt) * 64 + lane];
            lsacc[qb] += xv[(8 + qb) * 64 + lane];
#pragma unroll
            for (int rg = 0; rg < 4; rg++) {
                float inv = 1.0f / lsacc[qb][rg];
                size_t row = (size_t)(qrow_base + qb * 16 + quad * 4 + rg) * HDIM;
#pragma unroll
                for (int dt = 0; dt < 4; dt++)
                    op[row + dt * 16 + l15] = o_acc[qb][dt][rg] * inv;
            }
        }
    }
}

extern "C" void kernel_launch(void* const* d_in, const int* in_sizes, int n_in,
                              void* d_out, int out_size, void* d_ws, size_t ws_size,
                              hipStream_t stream) {
    const float* q = (const float*)d_in[0];
    const float* k = (const float*)d_in[1];
    const float* v = (const float*)d_in[2];
    float* out = (float*)d_out;

    u16* vt = (u16*)d_ws;                               // 8 MB bf16 V^T (permuted)

    prep<<<dim3(T_SEQ / 32, NBH), 256, 0, stream>>>(v, vt);
    fattn<<<dim3(512), 512, 0, stream>>>(q, k, vt, out);
}